// Round 3
// baseline (133.010 us; speedup 1.0000x reference)
//
#include <hip/hip_runtime.h>

// R8 = R7 + tile-row-chunked XCD swizzle (3-line bid remap, numerics untouched).
// HW round-robins consecutive blockIdx across the 8 XCDs (private L2s), so the
// x-adjacent tile that owns the other half of every 64/128B line lands on a
// DIFFERENT XCD -> ~2x HBM read over-fetch on img/re_mask (8x8 tiles touch 32B
// row segments). Remap so each XCD gets a contiguous 64-tile row: x-adjacent
// tiles dispatch back-to-back on the same XCD and the second half-line is an
// L2 hit. Row-granular (not batch-granular) chunks keep heavy tiles balanced
// across XCDs. Mapping bijective: 32768 = 64 groups x 8 xcd x 64 tiles.
//
// R7 structure (harness-verified, dur 109.2): single role, 32768 blocks = one
// per (tile,batch); copy role folded in; speculative img+re_mask prefetch
// before the sel branch; !sel -> barrier-free tile copy; all-ones -> tile copy;
// else heavy pipeline (verified R6 numerics, byte-identical).
// img_p (padded img+noise) radius 3 -> 14x14/ch; img_r radius 2 -> 12x12;
// img_3d_mod radius 1 -> 10x10.
#define TS 8
#define PW 14
#define PS 15   // LDS row stride (pad +1)
#define RW 12
#define RS 13
#define MW 10
#define MS 11

#define NTILES 32768   // 64 x 64 tiles x 8 batches

__global__ __launch_bounds__(256, 8)
void gdfn_fused(const float* __restrict__ img,
                const float* __restrict__ noise,
                const float* __restrict__ re_mask,
                const int*   __restrict__ sel,
                const int*   __restrict__ mix_sel,
                float*       __restrict__ out)
{
    constexpr int H = 512, W = 512, HP = 514, WP = 514;
    const int rawbid = blockIdx.x;
    // tile-row-chunked XCD swizzle: (hi:6 | lo:3 | mid:6) -> hi*512 + lo*64 + mid
    const int bid = ((rawbid >> 9) << 9) | ((rawbid & 7) << 6) | ((rawbid >> 3) & 63);
    const int tid = threadIdx.x;

    const int b  = bid >> 12;
    const int t  = bid & 4095;
    const int h0 = (t >> 6) * TS;
    const int w0 = (t & 63) * TS;

    const size_t HWs  = (size_t)H * W;
    const size_t imgB = (size_t)b * 3 * HWs;
    const size_t noiB = (size_t)b * 3 * HP * WP;

    // Speculative tile prefetch: img + re_mask (48 float4 each), issued before
    // any branch so both are in flight while sel[b] resolves via scalar cache.
    float4 pimg4, m4;
    size_t tpo = 0;
    int allone = 1;
    if (tid < 48) {
        int c = tid >> 4, r = tid & 15;
        int row = r >> 1, col4 = (r & 1) << 2;
        tpo = imgB + (size_t)c * HWs + (size_t)(h0 + row) * W + (w0 + col4);
        pimg4 = *(const float4*)(img + tpo);
        m4    = *(const float4*)(re_mask + tpo);
    }
    const int selb = sel[b];

    // ---- non-sel: this block IS the copy for its tile (no barrier) ----
    if (!selb) {
        if (tid < 48) *(float4*)(out + tpo) = pimg4;
        return;
    }

    if (tid < 48)
        allone = (m4.x == 1.f) & (m4.y == 1.f) & (m4.z == 1.f) & (m4.w == 1.f);
    allone = __syncthreads_and(allone);
    if (allone) {                           // out = img*1 exactly
        if (tid < 48) *(float4*)(out + tpo) = pimg4;
        return;
    }

    // ---------------- heavy pipeline (verified R6 code, unchanged) ----------------
    const int msel = mix_sel[b];

    // stage-3 per-(pixel,channel) loads issued early (threads 0..191)
    const int c3  = tid >> 6;              // 0..3 (c3==3 inactive in stage 3)
    const int p3i = tid & 63;
    const int t3y = p3i >> 3, t3x = p3i & 7;
    const int g3y = h0 + t3y, g3x = w0 + t3x;
    const size_t o3 = imgB + (size_t)c3 * HWs + (size_t)g3y * W + g3x;
    float img3v = 0.f, rm3v = 0.f;
    if (tid < 192) {
        img3v = img[o3];
        rm3v  = re_mask[o3];
    }

    __shared__ float s_imgp[3 * PW * PS];   // 2520 B
    __shared__ float s_w   [RW * RW * 9];   // w3 per stage-1 pixel, 5184 B
    __shared__ float s_imgr[RW * RS];       //  624 B
    __shared__ float s_mod [MW * MS];       //  440 B

    // Stage 0: img_p = pad(img,1)+noise over padded [h0-2, h0+11]^2, 588 elems.
#pragma unroll
    for (int it = 0; it < 3; ++it) {
        int idx = tid + it * 256;
        if (idx < 3 * PW * PW) {
            int c  = idx / (PW * PW);
            int r  = idx - c * (PW * PW);
            int ly = r / PW, lx = r - ly * PW;
            int py = h0 - 2 + ly, px = w0 - 2 + lx;   // padded coords
            float v = 0.f;
            if (py >= 0 && py < HP && px >= 0 && px < WP) {
                v = noise[noiB + (size_t)c * HP * WP + (size_t)py * WP + px];
                int iy = py - 1, ix = px - 1;
                if (iy >= 0 && iy < H && ix >= 0 && ix < W)
                    v += img[imgB + (size_t)c * HWs + (size_t)iy * W + ix];
            }
            s_imgp[c * PW * PS + ly * PS + lx] = v;
        }
    }
    __syncthreads();

    // Stage 1: per pixel (12x12 = 144 tasks), all 3 channels in registers.
    // w = exp(-(x-mean)^2/(2*std^2)), std^2(ddof=1) = ssd/8 => exp(-4 d^2/ssd)
    // Channel grouping (v0+v1)+v2 and k-order summation match the passing R5 kernel.
    if (tid < RW * RW) {
        int sy = tid / RW, sx = tid - sy * RW;
        int ry = h0 - 2 + sy, rx = w0 - 2 + sx;
        if (ry >= 0 && ry < H && rx >= 0 && rx < W) {
            float w3[9], vs[9];
#pragma unroll
            for (int c = 0; c < 3; ++c) {
                const float* sp = &s_imgp[c * PW * PS + sy * PS + sx];
                float v[9];
                float sum = 0.f;
#pragma unroll
                for (int i = 0; i < 3; ++i)
#pragma unroll
                    for (int j = 0; j < 3; ++j) {
                        float x = sp[i * PS + j];
                        v[i * 3 + j] = x;
                        sum += x;
                    }
                float mean = sum * (1.f / 9.f);
                float ssd = 0.f;
#pragma unroll
                for (int k = 0; k < 9; ++k) { float d = v[k] - mean; ssd += d * d; }
                float inv = -4.f / ssd;
#pragma unroll
                for (int k = 0; k < 9; ++k) {
                    float d  = v[k] - mean;
                    float wv = __expf(d * d * inv);   // native v_exp_f32 path
                    if (c == 0) { w3[k] = wv;              vs[k] = v[k];  }
                    else        { w3[k] = fminf(w3[k], wv); vs[k] += v[k]; }
                }
            }
            float num = 0.f, den = 0.f;
#pragma unroll
            for (int k = 0; k < 9; ++k) {
                den += w3[k];
                num += vs[k] * w3[k];
            }
            s_imgr[sy * RS + sx] = num / den;
            float* wd = &s_w[tid * 9];
#pragma unroll
            for (int k = 0; k < 9; ++k) wd[k] = w3[k];
        }
    }
    __syncthreads();

    // Stage 2: per pixel (10x10): first-occurrence argmin/argmax over img_r 3x3
    // (OOB = 0.0 exactly); selected weight read from cached w3.
    if (tid < MW * MW) {
        int my = tid / MW, mx = tid - my * MW;
        int qy = h0 - 1 + my, qx = w0 - 1 + mx;
        if (qy >= 0 && qy < H && qx >= 0 && qx < W) {
            float bmin = 0.f, bmax = 0.f;
            int imin = 0, imax = 0;
#pragma unroll
            for (int k = 0; k < 9; ++k) {
                int di = k / 3 - 1, dj = k % 3 - 1;
                int ny = qy + di, nx = qx + dj;
                float val = 0.f;
                if (ny >= 0 && ny < H && nx >= 0 && nx < W)
                    val = s_imgr[(my + 1 + di) * RS + (mx + 1 + dj)];
                if (k == 0) { bmin = val; bmax = val; }
                else {
                    if (val < bmin) { bmin = val; imin = k; }
                    if (val > bmax) { bmax = val; imax = k; }
                }
            }
            int ks = msel ? imax : imin;
            int rp = (my + 1) * RW + (mx + 1);   // stage-1 domain index of q
            s_mod[my * MS + mx] = s_w[rp * 9 + ks];
        }
    }
    __syncthreads();

    // Stage 3: per (pixel, channel), 192 threads: img_mod = sum(img_e*m_e)/sum(m_e).
    // mden recomputed per channel is bit-identical (same adds in same order).
    if (tid < 192) {
        float m[9];
        float mden = 0.f;
#pragma unroll
        for (int k = 0; k < 9; ++k) {
            int di = k / 3 - 1, dj = k % 3 - 1;
            int ny = g3y + di, nx = g3x + dj;
            float mv = 0.f;
            if (ny >= 0 && ny < H && nx >= 0 && nx < W)
                mv = s_mod[(t3y + di + 1) * MS + (t3x + dj + 1)];
            m[k] = mv;
            mden += mv;
        }
        const float* sp = &s_imgp[c3 * PW * PS + (t3y + 2) * PS + (t3x + 2)];
        float numc = 0.f;
#pragma unroll
        for (int i = 0; i < 3; ++i)
#pragma unroll
            for (int j = 0; j < 3; ++j)
                numc += sp[i * PS + j] * m[i * 3 + j];
        float imod = numc / mden;
        out[o3] = imod * (1.f - rm3v) + img3v * rm3v;
    }
}

extern "C" void kernel_launch(void* const* d_in, const int* in_sizes, int n_in,
                              void* d_out, int out_size, void* d_ws, size_t ws_size,
                              hipStream_t stream)
{
    const float* img     = (const float*)d_in[0];
    const float* noise   = (const float*)d_in[1];
    const float* re_mask = (const float*)d_in[2];
    const int*   sel     = (const int*)d_in[3];
    const int*   mix_sel = (const int*)d_in[4];
    float*       out     = (float*)d_out;

    dim3 grid(NTILES);   // one block per (tile, batch); copy role folded in
    hipLaunchKernelGGL(gdfn_fused, grid, dim3(256), 0, stream,
                       img, noise, re_mask, sel, mix_sel, out);
}

// Round 7
// 130.679 us; speedup vs baseline: 1.0178x; 1.0178x over previous
//
#include <hip/hip_runtime.h>

// R9 (fourth submit; R4/R5/R6 benches were GPUAcquisitionTimeouts, no signal):
// revert R8's XCD swizzle (measured -17us kernel regression; rawbid->XCD
// round-robin assumption falsified). Attack the measured 1.47x WRITE_SIZE
// amplification (36.9MB vs 25.2MB unique) at its root: 8x8 tiles touch 32B
// row-segments; L2 partial-dirty lines pay RFO + padded writeback, and reads
// waste half of every 64B line. Tile -> 16 wide x 8 tall: every row access
// (prefetch/copy/stage-3 store) is a full aligned 64B line, independent of
// XCD placement. Blocks 32768 -> 16384.
// Heavy pipeline re-indexed for the 22x14 halo; per-pixel arithmetic sequence
// is byte-identical to verified R6/R7 (channel grouping, k-order, OOB rules).
// img_p (padded img+noise) radius 3 -> 14x22/ch; img_r radius 2 -> 12x20;
// img_3d_mod radius 1 -> 10x18.
#define TSY 8
#define TSX 16
#define PWY 14
#define PWX 22
#define PS2 23   // LDS row stride (pad +1)
#define RWY 12
#define RWX 20
#define RS2 21
#define MWY 10
#define MWX 18
#define MS2 19

#define NTILES 16384   // 64 y-tiles x 32 x-tiles x 8 batches

__global__ __launch_bounds__(256, 8)
void gdfn_fused(const float* __restrict__ img,
                const float* __restrict__ noise,
                const float* __restrict__ re_mask,
                const int*   __restrict__ sel,
                const int*   __restrict__ mix_sel,
                float*       __restrict__ out)
{
    constexpr int H = 512, W = 512, HP = 514, WP = 514;
    const int bid = blockIdx.x;          // raw order (R8 swizzle reverted)
    const int tid = threadIdx.x;

    const int b  = bid >> 11;
    const int t  = bid & 2047;
    const int h0 = (t >> 5) * TSY;
    const int w0 = (t & 31) * TSX;

    const size_t HWs  = (size_t)H * W;
    const size_t imgB = (size_t)b * 3 * HWs;
    const size_t noiB = (size_t)b * 3 * HP * WP;

    // Speculative tile prefetch: img + re_mask, 96 float4 each (16x8x3 floats),
    // one full 64B line per row. Issued before any branch; sel[b] via s-cache.
    float4 pimg4, m4;
    size_t tpo = 0;
    int allone = 1;
    if (tid < 96) {
        int c = tid >> 5, r = tid & 31;
        int row = r >> 2, col4 = (r & 3) << 2;
        tpo = imgB + (size_t)c * HWs + (size_t)(h0 + row) * W + (w0 + col4);
        pimg4 = *(const float4*)(img + tpo);
        m4    = *(const float4*)(re_mask + tpo);
    }
    const int selb = sel[b];

    // ---- non-sel: this block IS the copy for its tile (no barrier) ----
    if (!selb) {
        if (tid < 96) *(float4*)(out + tpo) = pimg4;
        return;
    }

    if (tid < 96)
        allone = (m4.x == 1.f) & (m4.y == 1.f) & (m4.z == 1.f) & (m4.w == 1.f);
    allone = __syncthreads_and(allone);
    if (allone) {                           // out = img*1 exactly
        if (tid < 96) *(float4*)(out + tpo) = pimg4;
        return;
    }

    // ---------------- heavy pipeline (R6 numerics, re-indexed 16x8) ----------------
    const int msel = mix_sel[b];

    // stage-3 tasks: 384 = 128 pixels x 3 channels; thread owns task tid and
    // (tid<128) task tid+256. Global loads issued early for latency overlap.
    const int c3a  = tid >> 7;             // 0..1
    const int p3a  = tid & 127;
    const int t3ya = p3a >> 4, t3xa = p3a & 15;
    const size_t o3a = imgB + (size_t)c3a * HWs + (size_t)(h0 + t3ya) * W + (w0 + t3xa);
    float img3a = img[o3a];
    float rm3a  = re_mask[o3a];
    const int t3yb = tid >> 4, t3xb = tid & 15;     // task1: c=2, pixel=tid
    size_t o3b = 0; float img3b = 0.f, rm3b = 0.f;
    if (tid < 128) {
        o3b = imgB + (size_t)2 * HWs + (size_t)(h0 + t3yb) * W + (w0 + t3xb);
        img3b = img[o3b];
        rm3b  = re_mask[o3b];
    }

    __shared__ float s_imgp[3 * PWY * PS2];   // 966 f = 3864 B
    __shared__ float s_w   [RWY * RWX * 9];   // 2160 f = 8640 B
    __shared__ float s_imgr[RWY * RS2];       //  252 f = 1008 B
    __shared__ float s_mod [MWY * MS2];       //  190 f =  760 B

    // Stage 0: img_p = pad(img,1)+noise over padded [h0-2,h0+11] x [w0-2,w0+19],
    // 3*14*22 = 924 elems.
#pragma unroll
    for (int it = 0; it < 4; ++it) {
        int idx = tid + it * 256;
        if (idx < 3 * PWY * PWX) {
            int c  = idx / (PWY * PWX);
            int r  = idx - c * (PWY * PWX);
            int ly = r / PWX, lx = r - ly * PWX;
            int py = h0 - 2 + ly, px = w0 - 2 + lx;   // padded coords
            float v = 0.f;
            if (py >= 0 && py < HP && px >= 0 && px < WP) {
                v = noise[noiB + (size_t)c * HP * WP + (size_t)py * WP + px];
                int iy = py - 1, ix = px - 1;
                if (iy >= 0 && iy < H && ix >= 0 && ix < W)
                    v += img[imgB + (size_t)c * HWs + (size_t)iy * W + ix];
            }
            s_imgp[c * PWY * PS2 + ly * PS2 + lx] = v;
        }
    }
    __syncthreads();

    // Stage 1: per pixel (12x20 = 240 tasks), all 3 channels in registers.
    // w = exp(-(x-mean)^2/(2*std^2)), std^2(ddof=1) = ssd/8 => exp(-4 d^2/ssd)
    // Channel grouping (v0+v1)+v2 and k-order summation identical to R6/R7.
    if (tid < RWY * RWX) {
        int sy = tid / RWX, sx = tid - sy * RWX;
        int ry = h0 - 2 + sy, rx = w0 - 2 + sx;
        if (ry >= 0 && ry < H && rx >= 0 && rx < W) {
            float w3[9], vs[9];
#pragma unroll
            for (int c = 0; c < 3; ++c) {
                const float* sp = &s_imgp[c * PWY * PS2 + sy * PS2 + sx];
                float v[9];
                float sum = 0.f;
#pragma unroll
                for (int i = 0; i < 3; ++i)
#pragma unroll
                    for (int j = 0; j < 3; ++j) {
                        float x = sp[i * PS2 + j];
                        v[i * 3 + j] = x;
                        sum += x;
                    }
                float mean = sum * (1.f / 9.f);
                float ssd = 0.f;
#pragma unroll
                for (int k = 0; k < 9; ++k) { float d = v[k] - mean; ssd += d * d; }
                float inv = -4.f / ssd;
#pragma unroll
                for (int k = 0; k < 9; ++k) {
                    float d  = v[k] - mean;
                    float wv = __expf(d * d * inv);   // native v_exp_f32 path
                    if (c == 0) { w3[k] = wv;              vs[k] = v[k];  }
                    else        { w3[k] = fminf(w3[k], wv); vs[k] += v[k]; }
                }
            }
            float num = 0.f, den = 0.f;
#pragma unroll
            for (int k = 0; k < 9; ++k) {
                den += w3[k];
                num += vs[k] * w3[k];
            }
            s_imgr[sy * RS2 + sx] = num / den;
            float* wd = &s_w[tid * 9];
#pragma unroll
            for (int k = 0; k < 9; ++k) wd[k] = w3[k];
        }
    }
    __syncthreads();

    // Stage 2: per pixel (10x18 = 180): first-occurrence argmin/argmax over
    // img_r 3x3 (OOB = 0.0 exactly); selected weight read from cached w3.
    if (tid < MWY * MWX) {
        int my = tid / MWX, mx = tid - my * MWX;
        int qy = h0 - 1 + my, qx = w0 - 1 + mx;
        if (qy >= 0 && qy < H && qx >= 0 && qx < W) {
            float bmin = 0.f, bmax = 0.f;
            int imin = 0, imax = 0;
#pragma unroll
            for (int k = 0; k < 9; ++k) {
                int di = k / 3 - 1, dj = k % 3 - 1;
                int ny = qy + di, nx = qx + dj;
                float val = 0.f;
                if (ny >= 0 && ny < H && nx >= 0 && nx < W)
                    val = s_imgr[(my + 1 + di) * RS2 + (mx + 1 + dj)];
                if (k == 0) { bmin = val; bmax = val; }
                else {
                    if (val < bmin) { bmin = val; imin = k; }
                    if (val > bmax) { bmax = val; imax = k; }
                }
            }
            int ks = msel ? imax : imin;
            int rp = (my + 1) * RWX + (mx + 1);   // stage-1 domain index of q
            s_mod[my * MS2 + mx] = s_w[rp * 9 + ks];
        }
    }
    __syncthreads();

    // Stage 3: per (pixel, channel): img_mod = sum(img_e*m_e)/sum(m_e).
    // mden recomputed per channel is bit-identical (same adds in same order).
    {
        float m[9];
        float mden = 0.f;
#pragma unroll
        for (int k = 0; k < 9; ++k) {
            int di = k / 3 - 1, dj = k % 3 - 1;
            int ny = h0 + t3ya + di, nx = w0 + t3xa + dj;
            float mv = 0.f;
            if (ny >= 0 && ny < H && nx >= 0 && nx < W)
                mv = s_mod[(t3ya + di + 1) * MS2 + (t3xa + dj + 1)];
            m[k] = mv;
            mden += mv;
        }
        const float* sp = &s_imgp[c3a * PWY * PS2 + (t3ya + 2) * PS2 + (t3xa + 2)];
        float numc = 0.f;
#pragma unroll
        for (int i = 0; i < 3; ++i)
#pragma unroll
            for (int j = 0; j < 3; ++j)
                numc += sp[i * PS2 + j] * m[i * 3 + j];
        float imod = numc / mden;
        out[o3a] = imod * (1.f - rm3a) + img3a * rm3a;
    }
    if (tid < 128) {
        float m[9];
        float mden = 0.f;
#pragma unroll
        for (int k = 0; k < 9; ++k) {
            int di = k / 3 - 1, dj = k % 3 - 1;
            int ny = h0 + t3yb + di, nx = w0 + t3xb + dj;
            float mv = 0.f;
            if (ny >= 0 && ny < H && nx >= 0 && nx < W)
                mv = s_mod[(t3yb + di + 1) * MS2 + (t3xb + dj + 1)];
            m[k] = mv;
            mden += mv;
        }
        const float* sp = &s_imgp[2 * PWY * PS2 + (t3yb + 2) * PS2 + (t3xb + 2)];
        float numc = 0.f;
#pragma unroll
        for (int i = 0; i < 3; ++i)
#pragma unroll
            for (int j = 0; j < 3; ++j)
                numc += sp[i * PS2 + j] * m[i * 3 + j];
        float imod = numc / mden;
        out[o3b] = imod * (1.f - rm3b) + img3b * rm3b;
    }
}

extern "C" void kernel_launch(void* const* d_in, const int* in_sizes, int n_in,
                              void* d_out, int out_size, void* d_ws, size_t ws_size,
                              hipStream_t stream)
{
    const float* img     = (const float*)d_in[0];
    const float* noise   = (const float*)d_in[1];
    const float* re_mask = (const float*)d_in[2];
    const int*   sel     = (const int*)d_in[3];
    const int*   mix_sel = (const int*)d_in[4];
    float*       out     = (float*)d_out;

    dim3 grid(NTILES);   // one block per (16x8 tile, batch)
    hipLaunchKernelGGL(gdfn_fused, grid, dim3(256), 0, stream,
                       img, noise, re_mask, sel, mix_sel, out);
}